// Round 8
// baseline (125.217 us; speedup 1.0000x reference)
//
#include <hip/hip_runtime.h>
#include <hip/hip_bf16.h>
#include <cstdint>

#define BATCH   32
#define NVARS   16
#define SAMPLES 4096
#define EDIM    128
#define NTOK    1016          // (4096-32)/4
#define PLELEM  4368          // bf16 per plane slot = 8736 B (16B-aligned)

typedef __bf16 bf8_t __attribute__((ext_vector_type(8)));
typedef float  f4_t  __attribute__((ext_vector_type(4)));

// ---------------------------------------------------------------------------
// prep_kernel: W_patch repack ONLY.
// WtF[kb][g(8)][lane(64)][t(8)] = B[kbase(kb)+quad*8+t][g*16+l15]
//   (kbase=(4*dlt+(s&3))*128+(s>>2)*32, kb=s*8+dlt) -> a GEMM wave's
//   B-fragment group is one coalesced 1KB global load straight to VGPRs.
// ---------------------------------------------------------------------------
__global__ __launch_bounds__(256) void prep_kernel(
    const float* __restrict__ Wp, __hip_bfloat16* __restrict__ WtF)
{
  __shared__ float ls[32][132];
  int tid = threadIdx.x;
  int kb  = blockIdx.x;
  int s = kb >> 3, dlt = kb & 7;
  int kbase = (4 * dlt + (s & 3)) * 128 + (s >> 2) * 32;
#pragma unroll
  for (int r = 0; r < 16; ++r) {
    int idx = tid + r * 256;
    ls[idx >> 7][idx & 127] =
        Wp[(size_t)(kbase + (idx >> 7)) * EDIM + (idx & 127)];
  }
  __syncthreads();
  int g = tid >> 5, l5 = tid & 31;
#pragma unroll
  for (int h = 0; h < 2; ++h) {
    int lane = l5 + h * 32;
    int quad = lane >> 4, l15 = lane & 15;
    int n = g * 16 + l15;
    union { unsigned short u[8]; uint4 v; } pk;
#pragma unroll
    for (int t = 0; t < 8; ++t) {
      __hip_bfloat16 hh = __float2bfloat16(ls[quad * 8 + t][n]);
      pk.u[t] = *(unsigned short*)&hh;
    }
    *(uint4*)(WtF + (size_t)kb * 4096 + g * 512 + lane * 8) = pk.v;
  }
}

// ---------------------------------------------------------------------------
// R8 = R7 with __launch_bounds__(1024, 4).
// R7 post-mortem: bare (1024) made hipcc pick a 64-VGPR budget (8 waves/EU
// target) while the GEMM live set is ~124 -> ~110 MB/dispatch of scratch
// traffic (FETCH 39 MB, WRITE 71 MB) = the entire 61 us runtime.  The
// 4-waves/SIMD occupancy thesis never ran clean.  (1024,4): 512 regs/SIMD
// / 4 waves = 128 VGPR cap; GEMM live = 64 acc + 32 bq + 16 af + ~12 addr
// = ~124 <= 128; encode live ~90, phase-disjoint.  Single-token change.
//
// Structure recap (R7): phase-split fusion; 16 waves = 4 K-quarters (g2)
// x 2 N-halves (nh) x 2 M-halves (mh); wave tile 64x64, acc[4][4]; af[4]
// single-buffer (TLP replaces ILP); bq depth-2; encode 4.25 tasks/thread;
// barrier-free GEMM; 4-partial LDS reduction epilogue.  K-order, swizzle,
// summation order identical to R0-verified math.
// ---------------------------------------------------------------------------
__global__ __launch_bounds__(1024, 4) void fused_kernel(
    const float* __restrict__ x,
    const float* __restrict__ Ws,
    const float* __restrict__ bs,
    const __hip_bfloat16* __restrict__ WtF,
    const float* __restrict__ bp,
    float* __restrict__ out)
{
  __shared__ __align__(16) __hip_bfloat16 Apan[16 * PLELEM];  // 139,776 B
  __shared__ __align__(16) float xTp[2][136][16];             //  17,408 B

  int tid  = threadIdx.x;
  int lane = tid & 63;
  int wv   = tid >> 6;               // 0..15
  int g2   = wv >> 2;                // K-quarter 0..3
  int nh   = (wv >> 1) & 1;          // N-half
  int mh   = wv & 1;                 // M-half
  int b    = blockIdx.x >> 3;
  int t0   = (blockIdx.x & 7) << 7;
  int quad = lane >> 4;
  int l15  = lane & 15;

  const __hip_bfloat16* bg = WtF + (size_t)(nh * 4) * 512 + lane * 8;

  // ---------------- encode setup: fixed dim-quad per thread --------------
  int q4 = tid & 31;                 // dims 4*q4 .. 4*q4+3
  int eq = q4 >> 3;                  // e-block 0..3
  int cq = (q4 >> 1) & 3;            // 16B chunk within row
  int hq = q4 & 1;                   // 8B half within chunk
  int r0 = tid >> 5;                 // 0..31 (row base, +32j)

  float w[NVARS][4];
  float bz[4];
  {
    int d0 = q4 * 4;
#pragma unroll
    for (int v = 0; v < NVARS; ++v)
      *(float4*)&w[v][0] = *(const float4*)(Ws + v * EDIM + d0);
    *(float4*)&bz[0] = *(const float4*)(bs + d0);
  }

  // ---------------- x -> regs: (row, var), float4 = 4 phases -------------
  int vv = tid & 15, rr = tid >> 4;  // rr 0..63
  float4 xreg[3];
  {
    const float* xb = x + ((size_t)b * NVARS + vv) * SAMPLES;
    xreg[0] = *(const float4*)(xb + (t0 + rr) * 4);
    xreg[1] = *(const float4*)(xb + (t0 + 64 + rr) * 4);
    if (tid < 128) {                             // rows 128..135 (rr<8)
      int s4 = (t0 + 128 + rr) * 4;
      if (s4 > SAMPLES - 4) s4 = SAMPLES - 4;    // clamp (masked tokens only)
      xreg[2] = *(const float4*)(xb + s4);
    }
  }

  // ---------------- phase staging + encode -------------------------------
  auto stageX = [&](int p, int buf) {
    float c0 = (p == 0) ? xreg[0].x : (p == 1) ? xreg[0].y
             : (p == 2) ? xreg[0].z : xreg[0].w;
    float c1 = (p == 0) ? xreg[1].x : (p == 1) ? xreg[1].y
             : (p == 2) ? xreg[1].z : xreg[1].w;
    xTp[buf][rr][vv]      = c0;
    xTp[buf][64 + rr][vv] = c1;
    if (tid < 128) {
      float c2 = (p == 0) ? xreg[2].x : (p == 1) ? xreg[2].y
               : (p == 2) ? xreg[2].z : xreg[2].w;
      xTp[buf][128 + rr][vv] = c2;
    }
  };

  auto encTask = [&](int p, int buf, int r) {
    const float* xr = &xTp[buf][r][0];
    float xv[NVARS];
    *(float4*)&xv[0]  = *(const float4*)(xr + 0);
    *(float4*)&xv[4]  = *(const float4*)(xr + 4);
    *(float4*)&xv[8]  = *(const float4*)(xr + 8);
    *(float4*)&xv[12] = *(const float4*)(xr + 12);
    float a0 = bz[0], a1 = bz[1], a2 = bz[2], a3 = bz[3];
#pragma unroll
    for (int v = 0; v < NVARS; ++v) {
      a0 += xv[v] * w[v][0]; a1 += xv[v] * w[v][1];
      a2 += xv[v] * w[v][2]; a3 += xv[v] * w[v][3];
    }
    union { unsigned short us[4]; uint2 q; } pk;
    pk.us[0] = (unsigned short)(__float_as_uint(floorf(a0)) >> 16);
    pk.us[1] = (unsigned short)(__float_as_uint(floorf(a1)) >> 16);
    pk.us[2] = (unsigned short)(__float_as_uint(floorf(a2)) >> 16);
    pk.us[3] = (unsigned short)(__float_as_uint(floorf(a3)) >> 16);
    int phys = (cq + (r >> 1)) & 3;              // t0 contributes 0 mod 4
    char* plbase = (char*)&Apan[(eq * 4 + p) * PLELEM];
    *(uint2*)(plbase + r * 64 + phys * 16 + hq * 8) = pk.q;
  };

  stageX(0, 0);
  __syncthreads();
#pragma unroll
  for (int p = 0; p < 4; ++p) {
    if (p < 3) stageX(p + 1, (p + 1) & 1);
    int buf = p & 1;
#pragma unroll
    for (int j = 0; j < 4; ++j) encTask(p, buf, r0 + 32 * j);
    if (tid < 256) encTask(p, buf, 128 + (tid >> 5));
    __syncthreads();
  }
  // panel fully resident; no further A traffic, no barriers until epilogue

  // ---------------- GEMM main loop (barrier-free, 4K x 2N x 2M) ----------
  f4_t acc[4][4];
  f4_t zero = {0.f, 0.f, 0.f, 0.f};
#pragma unroll
  for (int i = 0; i < 4; ++i)
#pragma unroll
    for (int j = 0; j < 4; ++j) acc[i][j] = zero;

  auto loadB = [&](int kb, uint4* d) {
#pragma unroll
    for (int j = 0; j < 4; ++j)
      d[j] = *(const uint4*)(bg + (size_t)kb * 4096 + j * 512);
  };

  auto loadAF = [&](bf8_t* af, const bf8_t* pA, int dlt) {
    int swz = (quad + ((t0 + mh * 64 + dlt + l15) >> 1)) & 3;
#pragma unroll
    for (int i = 0; i < 4; ++i)
      af[i] = pA[(mh * 64 + dlt + i * 16 + l15) * 4 + swz];
  };

  auto mstep = [&](const bf8_t* af, const uint4* bq_) {
    __builtin_amdgcn_s_setprio(1);
#pragma unroll
    for (int mi = 0; mi < 4; ++mi)
#pragma unroll
      for (int ni = 0; ni < 4; ++ni)
        acc[mi][ni] = __builtin_amdgcn_mfma_f32_16x16x32_bf16(
            af[mi], __builtin_bit_cast(bf8_t, bq_[ni]), acc[mi][ni], 0, 0, 0);
    __builtin_amdgcn_s_setprio(0);
  };

  bf8_t af[4];
  uint4 bq[2][4];
  loadB(g2 * 32 + 0, bq[0]);
  loadB(g2 * 32 + 1, bq[1]);

  for (int ss = 0; ss < 4; ++ss) {
    const bf8_t* pA = (const bf8_t*)&Apan[(g2 * 4 + ss) * PLELEM];
#pragma unroll
    for (int d = 0; d < 8; ++d) {
      int kl = ss * 8 + d;
      loadAF(af, pA, d);
      mstep(af, bq[d & 1]);
      if (kl < 30) loadB(g2 * 32 + kl + 2, bq[d & 1]);
    }
  }

  // ---- 4-partial K reduction (g2 1..3 -> g2 0) + fused epilogue ----
  // rb2: 768 slots x 20 floats over Apan (61,440 B).  1 mi per round,
  // 4 rounds.  Writers: 12 waves (g2>0); readers: 4 waves (g2==0).
  float* rb2 = (float*)&Apan[0];
  int idx4 = nh * 2 + mh;
  float bias[4];
#pragma unroll
  for (int ni = 0; ni < 4; ++ni) bias[ni] = bp[(nh << 6) + ni * 16 + l15];

#pragma unroll
  for (int rd = 0; rd < 4; ++rd) {
    __syncthreads();
    if (g2 > 0) {
      int slot = ((g2 - 1) * 4 + idx4) * 64 + lane;
#pragma unroll
      for (int ni = 0; ni < 4; ++ni)
        *(f4_t*)&rb2[(size_t)slot * 20 + ni * 4] = acc[rd][ni];
    }
    __syncthreads();
    if (g2 == 0) {
      f4_t s0 = acc[rd][0], s1 = acc[rd][1];
      f4_t s2 = acc[rd][2], s3 = acc[rd][3];
#pragma unroll
      for (int q = 1; q < 4; ++q) {
        int sl = ((q - 1) * 4 + idx4) * 64 + lane;
        s0 += *(const f4_t*)&rb2[(size_t)sl * 20 + 0];
        s1 += *(const f4_t*)&rb2[(size_t)sl * 20 + 4];
        s2 += *(const f4_t*)&rb2[(size_t)sl * 20 + 8];
        s3 += *(const f4_t*)&rb2[(size_t)sl * 20 + 12];
      }
      f4_t sv[4] = {s0, s1, s2, s3};
#pragma unroll
      for (int ni = 0; ni < 4; ++ni)
#pragma unroll
        for (int r = 0; r < 4; ++r) {
          int t = t0 + mh * 64 + rd * 16 + quad * 4 + r;
          if (t < NTOK) {
            int n = (nh << 6) + ni * 16 + l15;
            out[((size_t)b * NTOK + t) * EDIM + n] =
                floorf(sv[ni][r] + bias[ni]);
          }
        }
    }
  }
}

// ---------------------------------------------------------------------------
extern "C" void kernel_launch(void* const* d_in, const int* in_sizes, int n_in,
                              void* d_out, int out_size, void* d_ws, size_t ws_size,
                              hipStream_t stream) {
  const float* x  = (const float*)d_in[0];
  const float* Ws = (const float*)d_in[1];
  const float* bs = (const float*)d_in[2];
  const float* Wp = (const float*)d_in[3];
  const float* bp = (const float*)d_in[4];
  float* out = (float*)d_out;

  __hip_bfloat16* WtF = (__hip_bfloat16*)d_ws;   // 1 MB fragment-major B

  prep_kernel<<<128, 256, 0, stream>>>(Wp, WtF);
  fused_kernel<<<BATCH * 8, 1024, 0, stream>>>(x, Ws, bs, WtF, bp, out);
}

// Round 9
// 110.226 us; speedup vs baseline: 1.1360x; 1.1360x over previous
//
#include <hip/hip_runtime.h>
#include <hip/hip_bf16.h>
#include <cstdint>

#define BATCH   32
#define NVARS   16
#define SAMPLES 4096
#define EDIM    128
#define NTOK    1016          // (4096-32)/4
#define NROWS   72            // u-rows per 64-token tile (64 + 7 overlap, padded to 72)
#define PLELEM  2320          // bf16 per plane slot = 72*32 + 16 pad = 4640 B
                              // (16B-aligned; 4640/4 mod 32 = 8 -> +8-bank stagger/plane)

typedef __bf16 bf8_t __attribute__((ext_vector_type(8)));
typedef float  f4_t  __attribute__((ext_vector_type(4)));

// ---------------------------------------------------------------------------
// prep_kernel: W_patch repack ONLY.
// WtF[kb][g(8)][lane(64)][t(8)] = B[kbase(kb)+quad*8+t][g*16+l15]
//   (kbase=(4*dlt+(s&3))*128+(s>>2)*32, kb=s*8+dlt) -> a GEMM wave's
//   B-fragment group is one coalesced 1KB global load straight to VGPRs.
// ---------------------------------------------------------------------------
__global__ __launch_bounds__(256) void prep_kernel(
    const float* __restrict__ Wp, __hip_bfloat16* __restrict__ WtF)
{
  __shared__ float ls[32][132];
  int tid = threadIdx.x;
  int kb  = blockIdx.x;
  int s = kb >> 3, dlt = kb & 7;
  int kbase = (4 * dlt + (s & 3)) * 128 + (s >> 2) * 32;
#pragma unroll
  for (int r = 0; r < 16; ++r) {
    int idx = tid + r * 256;
    ls[idx >> 7][idx & 127] =
        Wp[(size_t)(kbase + (idx >> 7)) * EDIM + (idx & 127)];
  }
  __syncthreads();
  int g = tid >> 5, l5 = tid & 31;
#pragma unroll
  for (int h = 0; h < 2; ++h) {
    int lane = l5 + h * 32;
    int quad = lane >> 4, l15 = lane & 15;
    int n = g * 16 + l15;
    union { unsigned short u[8]; uint4 v; } pk;
#pragma unroll
    for (int t = 0; t < 8; ++t) {
      __hip_bfloat16 hh = __float2bfloat16(ls[quad * 8 + t][n]);
      pk.u[t] = *(unsigned short*)&hh;
    }
    *(uint4*)(WtF + (size_t)kb * 4096 + g * 512 + lane * 8) = pk.v;
  }
}

// ---------------------------------------------------------------------------
// R9: 64-token tile, 2 blocks/CU (occupancy via LDS halving).
// R7/R8 post-mortem: 1024-thread blocks are hard-capped at 64 VGPR by the
// allocator heuristic (launch_bounds 2nd arg is a MIN, can't lower the
// occupancy target) -> unfixable spills.  Proven-good budget: 512 threads
// + (512,2) -> 128 VGPR cap.  R9 reaches 4 waves/SIMD the other way:
// TB=64 tokens, LDS 78.8 KB -> 2 blocks/CU x 8 waves.  Bonus: block A's
// serial encode/epilogue overlaps block B's GEMM on the same CU.
//
// Panel: 16 planes (eblk x phase) x 72 rows x 32 dims bf16, +16-pad/plane.
// Encode: x in regs (float4 = 4 phases/row); per phase: stage column ->
// barrier -> 4.5 encTasks/thread (broadcast b128 reads, 2 rows/wave on
// banks {0-15},{16-31}) -> barrier.  Summation v-ascending f32 ->
// bit-identical enc.  Swizzle: t0 = 0 mod 64 -> (t0+r)>>1 = r>>1 mod 4;
// write phys=(cq+(r>>1))&3, read swz=(quad+((d+l15)>>1))&3; i*16 term
// drops exactly ((a+16i)>>1 = (a>>1)+8i).  GEMM: 8 waves = 4 K-quarters
// (g2) x 2 N-halves (nh), tile 64x64, acc[4][4]; kb = g2*32+ss*8+d,
// plane e=g2,p=ss (s=kb>>3=g2*4+ss) -> bit-identical K-order.  bq depth-2,
// af single-buffer (TLP hides LDS latency).  GEMM live ~112 <= 128.
// ---------------------------------------------------------------------------
__global__ __launch_bounds__(512, 2) void fused_kernel(
    const float* __restrict__ x,
    const float* __restrict__ Ws,
    const float* __restrict__ bs,
    const __hip_bfloat16* __restrict__ WtF,
    const float* __restrict__ bp,
    float* __restrict__ out)
{
  __shared__ __align__(16) __hip_bfloat16 Apan[16 * PLELEM];  // 74,240 B
  __shared__ __align__(16) float xT[NROWS][16];               //  4,608 B

  int tid  = threadIdx.x;
  int lane = tid & 63;
  int wv   = tid >> 6;               // 0..7
  int g2   = wv >> 1;                // K-quarter 0..3
  int nh   = wv & 1;                 // N-half
  int b    = blockIdx.x >> 4;
  int t0   = (blockIdx.x & 15) << 6; // 64-token tile
  int quad = lane >> 4;
  int l15  = lane & 15;

  const __hip_bfloat16* bg = WtF + (size_t)(nh * 4) * 512 + lane * 8;

  // ---------------- encode setup: fixed dim-quad per thread --------------
  int q4 = tid & 31;                 // dims 4*q4 .. 4*q4+3
  int eq = q4 >> 3;                  // e-block 0..3
  int cq = (q4 >> 1) & 3;            // 16B chunk within row
  int hq = q4 & 1;                   // 8B half within chunk
  int r0 = tid >> 5;                 // 0..15 (row base, +16j)

  float w[NVARS][4];
  float bz[4];
  {
    int d0 = q4 * 4;
#pragma unroll
    for (int v = 0; v < NVARS; ++v)
      *(float4*)&w[v][0] = *(const float4*)(Ws + v * EDIM + d0);
    *(float4*)&bz[0] = *(const float4*)(bs + d0);
  }

  // ---------------- x -> regs: (row, var), float4 = 4 phases -------------
  int vv = tid & 15, rr = tid >> 4;  // rr 0..31
  float4 xreg[3];
  {
    const float* xb = x + ((size_t)b * NVARS + vv) * SAMPLES;
    xreg[0] = *(const float4*)(xb + (t0 + rr) * 4);        // rows 0..31
    xreg[1] = *(const float4*)(xb + (t0 + 32 + rr) * 4);   // rows 32..63 (max s 4095)
    if (tid < 128) {                                       // rows 64..71 (rr<8)
      int s4 = (t0 + 64 + rr) * 4;
      if (s4 > SAMPLES - 4) s4 = SAMPLES - 4;              // clamp (masked tokens only)
      xreg[2] = *(const float4*)(xb + s4);
    }
  }

  auto encTask = [&](int p, int r) {
    const float* xr = &xT[r][0];
    float xv[NVARS];
    *(float4*)&xv[0]  = *(const float4*)(xr + 0);
    *(float4*)&xv[4]  = *(const float4*)(xr + 4);
    *(float4*)&xv[8]  = *(const float4*)(xr + 8);
    *(float4*)&xv[12] = *(const float4*)(xr + 12);
    float a0 = bz[0], a1 = bz[1], a2 = bz[2], a3 = bz[3];
#pragma unroll
    for (int v = 0; v < NVARS; ++v) {
      a0 += xv[v] * w[v][0]; a1 += xv[v] * w[v][1];
      a2 += xv[v] * w[v][2]; a3 += xv[v] * w[v][3];
    }
    union { unsigned short us[4]; uint2 q; } pk;
    pk.us[0] = (unsigned short)(__float_as_uint(floorf(a0)) >> 16);
    pk.us[1] = (unsigned short)(__float_as_uint(floorf(a1)) >> 16);
    pk.us[2] = (unsigned short)(__float_as_uint(floorf(a2)) >> 16);
    pk.us[3] = (unsigned short)(__float_as_uint(floorf(a3)) >> 16);
    int phys = (cq + (r >> 1)) & 3;              // t0 contributes 0 mod 4
    char* plbase = (char*)&Apan[(eq * 4 + p) * PLELEM];
    *(uint2*)(plbase + r * 64 + phys * 16 + hq * 8) = pk.q;
  };

  // ---------------- phase staging + encode (single xT buffer) ------------
#pragma unroll
  for (int p = 0; p < 4; ++p) {
    float c0 = (p == 0) ? xreg[0].x : (p == 1) ? xreg[0].y
             : (p == 2) ? xreg[0].z : xreg[0].w;
    float c1 = (p == 0) ? xreg[1].x : (p == 1) ? xreg[1].y
             : (p == 2) ? xreg[1].z : xreg[1].w;
    xT[rr][vv]      = c0;
    xT[32 + rr][vv] = c1;
    if (tid < 128) {
      float c2 = (p == 0) ? xreg[2].x : (p == 1) ? xreg[2].y
               : (p == 2) ? xreg[2].z : xreg[2].w;
      xT[64 + rr][vv] = c2;
    }
    __syncthreads();
#pragma unroll
    for (int j = 0; j < 4; ++j) encTask(p, r0 + 16 * j);
    if (tid < 256) encTask(p, 64 + (tid >> 5));
    __syncthreads();
  }
  // panel fully resident; no further A traffic, no barriers until epilogue

  // ---------------- GEMM main loop (barrier-free, 4K x 2N) ---------------
  f4_t acc[4][4];
  f4_t zero = {0.f, 0.f, 0.f, 0.f};
#pragma unroll
  for (int i = 0; i < 4; ++i)
#pragma unroll
    for (int j = 0; j < 4; ++j) acc[i][j] = zero;

  auto loadB = [&](int kb, uint4* d) {
#pragma unroll
    for (int j = 0; j < 4; ++j)
      d[j] = *(const uint4*)(bg + (size_t)kb * 4096 + j * 512);
  };

  auto loadAF = [&](bf8_t* af, const bf8_t* pA, int dlt) {
    int swz = (quad + ((dlt + l15) >> 1)) & 3;   // t0, i*16 drop mod 4
#pragma unroll
    for (int i = 0; i < 4; ++i)
      af[i] = pA[(dlt + i * 16 + l15) * 4 + swz];
  };

  auto mstep = [&](const bf8_t* af, const uint4* bq_) {
    __builtin_amdgcn_s_setprio(1);
#pragma unroll
    for (int mi = 0; mi < 4; ++mi)
#pragma unroll
      for (int ni = 0; ni < 4; ++ni)
        acc[mi][ni] = __builtin_amdgcn_mfma_f32_16x16x32_bf16(
            af[mi], __builtin_bit_cast(bf8_t, bq_[ni]), acc[mi][ni], 0, 0, 0);
    __builtin_amdgcn_s_setprio(0);
  };

  bf8_t af[4];
  uint4 bq[2][4];
  loadB(g2 * 32 + 0, bq[0]);
  loadB(g2 * 32 + 1, bq[1]);

  for (int ss = 0; ss < 4; ++ss) {
    const bf8_t* pA = (const bf8_t*)&Apan[(g2 * 4 + ss) * PLELEM];
#pragma unroll
    for (int d = 0; d < 8; ++d) {
      int kl = ss * 8 + d;
      loadAF(af, pA, d);
      mstep(af, bq[d & 1]);
      if (kl < 30) loadB(g2 * 32 + kl + 2, bq[d & 1]);
    }
  }

  // ---- 4-partial K reduction (g2 1..3 -> g2 0) + fused epilogue ----
  // rb2: 384 slots x 20 floats (30,720 B over Apan).  Stride-20 b128:
  // lanes 0-7 tile all 32 banks exactly once -> throughput-balanced.
  float* rb2 = (float*)&Apan[0];
  float bias[4];
#pragma unroll
  for (int ni = 0; ni < 4; ++ni) bias[ni] = bp[(nh << 6) + ni * 16 + l15];

#pragma unroll
  for (int rd = 0; rd < 4; ++rd) {
    __syncthreads();
    if (g2 > 0) {
      int slot = ((g2 - 1) * 2 + nh) * 64 + lane;
#pragma unroll
      for (int ni = 0; ni < 4; ++ni)
        *(f4_t*)&rb2[(size_t)slot * 20 + ni * 4] = acc[rd][ni];
    }
    __syncthreads();
    if (g2 == 0) {
      f4_t s0 = acc[rd][0], s1 = acc[rd][1];
      f4_t s2 = acc[rd][2], s3 = acc[rd][3];
#pragma unroll
      for (int q = 1; q < 4; ++q) {
        int sl = ((q - 1) * 2 + nh) * 64 + lane;
        s0 += *(const f4_t*)&rb2[(size_t)sl * 20 + 0];
        s1 += *(const f4_t*)&rb2[(size_t)sl * 20 + 4];
        s2 += *(const f4_t*)&rb2[(size_t)sl * 20 + 8];
        s3 += *(const f4_t*)&rb2[(size_t)sl * 20 + 12];
      }
      f4_t sv[4] = {s0, s1, s2, s3};
#pragma unroll
      for (int ni = 0; ni < 4; ++ni)
#pragma unroll
        for (int r = 0; r < 4; ++r) {
          int t = t0 + rd * 16 + quad * 4 + r;
          if (t < NTOK) {
            int n = (nh << 6) + ni * 16 + l15;
            out[((size_t)b * NTOK + t) * EDIM + n] =
                floorf(sv[ni][r] + bias[ni]);
          }
        }
    }
  }
}

// ---------------------------------------------------------------------------
extern "C" void kernel_launch(void* const* d_in, const int* in_sizes, int n_in,
                              void* d_out, int out_size, void* d_ws, size_t ws_size,
                              hipStream_t stream) {
  const float* x  = (const float*)d_in[0];
  const float* Ws = (const float*)d_in[1];
  const float* bs = (const float*)d_in[2];
  const float* Wp = (const float*)d_in[3];
  const float* bp = (const float*)d_in[4];
  float* out = (float*)d_out;

  __hip_bfloat16* WtF = (__hip_bfloat16*)d_ws;   // 1 MB fragment-major B

  prep_kernel<<<128, 256, 0, stream>>>(Wp, WtF);
  fused_kernel<<<BATCH * 16, 512, 0, stream>>>(x, Ws, bs, WtF, bp, out);
}